// Round 3
// 235.490 us; speedup vs baseline: 1.0335x; 1.0335x over previous
//
#include <hip/hip_runtime.h>
#include <stdint.h>

#define DM   1024
#define NH   16
#define DKH  64
#define SEQ  2048
#define NB   2

typedef __attribute__((ext_vector_type(8))) short  frag8;
typedef __attribute__((ext_vector_type(4))) short  frag4;
typedef __attribute__((ext_vector_type(4))) short  short4v;
typedef __attribute__((ext_vector_type(8))) short  short8v;
typedef __attribute__((ext_vector_type(4))) float  f32x4;

__device__ __forceinline__ unsigned short f2bf(float x){
  unsigned u = __float_as_uint(x);
  u += 0x7fffu + ((u >> 16) & 1u);
  return (unsigned short)(u >> 16);
}

// exp2 via the raw intrinsic (v_exp_f32) — avoids glibc __exp2f macro collision
__device__ __forceinline__ float dev_exp2(float x){
  return __builtin_amdgcn_exp2f(x);
}

#define GLOAD16(GP, LP) __builtin_amdgcn_global_load_lds( \
    (__attribute__((address_space(1))) void*)(GP), \
    (__attribute__((address_space(3))) void*)(LP), 16, 0, 0)

// Compiler memory fence (zero instructions): raw s_barrier is NOT an LLVM memory
// fence, so dependent LDS reads can be hoisted above it. Pin them below.
#define LDSFENCE() do{ asm volatile("" ::: "memory"); \
                       __builtin_amdgcn_sched_barrier(0); }while(0)

// 16B XOR swizzle: LDS granule g of row r holds global granule g^(r&7);
// staging loads global granule (lane&7)^row. (R4: conflicts -> 0 on b128 reads.)

// ---------------- cast fp32 -> bf16 for Q,K,V ----------------
__global__ __launch_bounds__(256) void cast_qkv(const float* __restrict__ Q,
                                                const float* __restrict__ K,
                                                const float* __restrict__ V,
                                                short* __restrict__ dst){
  const int z = blockIdx.z;
  const float* src = (z == 0) ? Q : (z == 1 ? K : V);
  const int i = (blockIdx.x * 256 + threadIdx.x) * 4;
  float4 f = *(const float4*)(src + i);
  short4v s;
  s.x = (short)f2bf(f.x); s.y = (short)f2bf(f.y);
  s.z = (short)f2bf(f.z); s.w = (short)f2bf(f.w);
  *(short4v*)(dst + (long)z * (SEQ*NB*DM) + i) = s;
}

// ---------------- weight transpose + cast: W(K,N) -> Wt(N,K) bf16 ----------------
__global__ __launch_bounds__(256) void wtrans(const float* __restrict__ Wq,
                                              const float* __restrict__ Wk,
                                              const float* __restrict__ Wv,
                                              const float* __restrict__ Wo,
                                              short* __restrict__ wt){
  const int z = blockIdx.z;
  const float* W = (z == 0) ? Wq : (z == 1 ? Wk : (z == 2 ? Wv : Wo));
  short* out = wt + (long)z * (DM*DM);
  __shared__ float t[32][33];
  const int n0 = blockIdx.x * 32, k0 = blockIdx.y * 32;
  const int c = threadIdx.x & 31, r0 = threadIdx.x >> 5;
#pragma unroll
  for (int i = 0; i < 4; ++i){
    int r = r0 + i * 8;
    t[r][c] = W[(k0 + r) * DM + n0 + c];
  }
  __syncthreads();
#pragma unroll
  for (int i = 0; i < 4; ++i){
    int r = r0 + i * 8;
    out[(n0 + r) * DM + k0 + c] = (short)f2bf(t[c][r]);
  }
}

// ---------------- 128x128 bf16 MFMA GEMM: C = A(M,K) * Bt(N,K)^T, +bias, *scale ----
__device__ __forceinline__ void store_out(short* p, float v){ *p = (short)f2bf(v); }
__device__ __forceinline__ void store_out(float* p, float v){ *p = v; }

template<typename OT>
__global__ __launch_bounds__(256) void gemm_bt(const short* __restrict__ Abase, long Astride,
                                               const short* __restrict__ Btbase, long Btstride,
                                               const float* __restrict__ bias0,
                                               const float* __restrict__ bias1,
                                               const float* __restrict__ bias2,
                                               OT* __restrict__ Cbase, long Cstride,
                                               float qscale){
  const int z = blockIdx.z;
  const short* A  = Abase + (long)z * Astride;
  const short* Bt = Btbase + (long)z * Btstride;
  OT* C = Cbase + (long)z * Cstride;
  const float* bias = (z == 0) ? bias0 : (z == 1 ? bias1 : bias2);
  const float scale = (z == 0) ? qscale : 1.0f;
  const int KD = DM, ND = DM;

  __shared__ __align__(16) short As[128 * 64];
  __shared__ __align__(16) short Bs[128 * 64];

  const int tid = threadIdx.x;
  const int w = tid >> 6, lane = tid & 63, l15 = lane & 15, quad = lane >> 4;
  const int wy = w >> 1, wx = w & 1;
  const int bm = blockIdx.x * 128, bn = blockIdx.y * 128;
  const int lrow = lane >> 3;
  const int lcolsw = (((lane & 7) ^ lrow) & 7) * 8;   // swizzled source granule

  f32x4 acc[4][4] = {};

  for (int kt = 0; kt < KD; kt += 64){
#pragma unroll
    for (int i = 0; i < 4; ++i){
      int j = w * 4 + i;
      GLOAD16(A  + (bm + j * 8 + lrow) * KD + kt + lcolsw, &As[j * 512]);
      GLOAD16(Bt + (bn + j * 8 + lrow) * KD + kt + lcolsw, &Bs[j * 512]);
    }
    __syncthreads();
#pragma unroll
    for (int ks = 0; ks < 2; ++ks){
      frag8 af[4], bf_[4];
#pragma unroll
      for (int mt = 0; mt < 4; ++mt)
        af[mt] = *(const frag8*)&As[(wy * 64 + mt * 16 + l15) * 64 +
                                    (((ks * 4 + quad) ^ (l15 & 7)) * 8)];
#pragma unroll
      for (int nt = 0; nt < 4; ++nt)
        bf_[nt] = *(const frag8*)&Bs[(wx * 64 + nt * 16 + l15) * 64 +
                                     (((ks * 4 + quad) ^ (l15 & 7)) * 8)];
#pragma unroll
      for (int mt = 0; mt < 4; ++mt)
#pragma unroll
        for (int nt = 0; nt < 4; ++nt)
          acc[mt][nt] = __builtin_amdgcn_mfma_f32_16x16x32_bf16(af[mt], bf_[nt], acc[mt][nt], 0, 0, 0);
    }
    __syncthreads();
  }

#pragma unroll
  for (int mt = 0; mt < 4; ++mt){
#pragma unroll
    for (int r = 0; r < 4; ++r){
      int m = bm + wy * 64 + mt * 16 + quad * 4 + r;
#pragma unroll
      for (int nt = 0; nt < 4; ++nt){
        int n = bn + wx * 64 + nt * 16 + l15;
        float v = (acc[mt][nt][r] + bias[n]) * scale;
        store_out(&C[(long)m * ND + n], v);
      }
    }
  }
}

// ---------------- 64x128-tile GEMM (for low-block-count output projection) -------
template<typename OT>
__global__ __launch_bounds__(256) void gemm64_bt(const short* __restrict__ A,
                                                 const short* __restrict__ Bt,
                                                 const float* __restrict__ bias,
                                                 OT* __restrict__ C,
                                                 float scale){
  const int KD = DM, ND = DM;
  __shared__ __align__(16) short As[64 * 64];
  __shared__ __align__(16) short Bs[128 * 64];
  const int tid = threadIdx.x;
  const int w = tid >> 6, lane = tid & 63, l15 = lane & 15, quad = lane >> 4;
  const int wy = w >> 1, wx = w & 1;
  const int bm = blockIdx.x * 64, bn = blockIdx.y * 128;
  const int lrow = lane >> 3;
  const int lcolsw = (((lane & 7) ^ lrow) & 7) * 8;
  f32x4 acc[2][4] = {};

  for (int kt = 0; kt < KD; kt += 64){
#pragma unroll
    for (int i = 0; i < 2; ++i){
      int j = w * 2 + i;
      GLOAD16(A + (bm + j * 8 + lrow) * KD + kt + lcolsw, &As[j * 512]);
    }
#pragma unroll
    for (int i = 0; i < 4; ++i){
      int j = w * 4 + i;
      GLOAD16(Bt + (bn + j * 8 + lrow) * KD + kt + lcolsw, &Bs[j * 512]);
    }
    __syncthreads();
#pragma unroll
    for (int ks = 0; ks < 2; ++ks){
      frag8 af[2], bf_[4];
#pragma unroll
      for (int mt = 0; mt < 2; ++mt)
        af[mt] = *(const frag8*)&As[(wy * 32 + mt * 16 + l15) * 64 +
                                    (((ks * 4 + quad) ^ (l15 & 7)) * 8)];
#pragma unroll
      for (int nt = 0; nt < 4; ++nt)
        bf_[nt] = *(const frag8*)&Bs[(wx * 64 + nt * 16 + l15) * 64 +
                                     (((ks * 4 + quad) ^ (l15 & 7)) * 8)];
#pragma unroll
      for (int mt = 0; mt < 2; ++mt)
#pragma unroll
        for (int nt = 0; nt < 4; ++nt)
          acc[mt][nt] = __builtin_amdgcn_mfma_f32_16x16x32_bf16(af[mt], bf_[nt], acc[mt][nt], 0, 0, 0);
    }
    __syncthreads();
  }

#pragma unroll
  for (int mt = 0; mt < 2; ++mt){
#pragma unroll
    for (int r = 0; r < 4; ++r){
      int m = bm + wy * 32 + mt * 16 + quad * 4 + r;
#pragma unroll
      for (int nt = 0; nt < 4; ++nt){
        int n = bn + wx * 64 + nt * 16 + l15;
        store_out(&C[(long)m * ND + n], (acc[mt][nt][r] + bias[n]) * scale);
      }
    }
  }
}

// ---------------- v (B*S, DM) -> vt (B,H,Dk,S) bf16 transpose ----------------
__global__ __launch_bounds__(256) void vtrans(const short* __restrict__ v,
                                              short* __restrict__ vt){
  const int bh = blockIdx.y;       // b*16+h
  const int b = bh >> 4, h = bh & 15;
  const int s0 = blockIdx.x * 64;
  __shared__ short tT[64][66];
  const short* vb = v + ((long)(b * SEQ + s0)) * DM + h * DKH;
  for (int j = threadIdx.x; j < 512; j += 256){
    int row = j >> 3, off = (j & 7) * 8;
    short8v d = *(const short8v*)(vb + row * DM + off);
#pragma unroll
    for (int e = 0; e < 8; ++e) tT[off + e][row] = d[e];
  }
  __syncthreads();
  short* out = vt + (long)bh * (DKH * SEQ) + s0;
  for (int j = threadIdx.x; j < 512; j += 256){
    int dr = j >> 3, soff = (j & 7) * 8;
    short8v o;
#pragma unroll
    for (int e = 0; e < 8; ++e) o[e] = tT[dr][soff + e];
    *(short8v*)(out + dr * SEQ + soff) = o;
  }
}

// ---------------- flash attention v11: BISECT -------------------------------------
// Compute body = v8 VERBATIM (linear K staging, K=16 _1k PV, manual bf16 pack,
// ones4-L) — the code that passed at 244us. The ONLY change vs v8 is the staging
// schedule: 3-buffer LDS, depth-2 prefetch, raw s_barrier + counted vmcnt(8)
// (never 0 in the main loop), lgkmcnt(0)+sched_barrier before the WAR barrier,
// setprio(1) around compute. If this fails, the pipeline is the v9/v10 fault;
// if it passes, the permuted-K K=32 PV was.
__global__ __launch_bounds__(256) void flash(const short* __restrict__ q,
                                             const short* __restrict__ k,
                                             const short* __restrict__ vt,
                                             short* __restrict__ comb){
  const int bh = blockIdx.y;
  const int b = bh >> 4, h = bh & 15;
  const int q0 = blockIdx.x * 128;         // 128 Q-rows per block, 32 per wave
  const int tid = threadIdx.x;
  const int w = tid >> 6, lane = tid & 63, l15 = lane & 15, quad = lane >> 4;

  __shared__ __align__(16) short Ks[3][64 * 64];
  __shared__ __align__(16) short Vs[3][64 * 64];

  // preload Q fragments straight from global (used as MFMA B operand)
  frag8 aq[2][2];
  const short* qb = q + ((long)(b * SEQ + q0 + w * 32)) * DM + h * DKH;
#pragma unroll
  for (int mt = 0; mt < 2; ++mt)
#pragma unroll
    for (int ks = 0; ks < 2; ++ks)
      aq[mt][ks] = *(const frag8*)(qb + (mt * 16 + l15) * DM + ks * 32 + quad * 8);

  frag4 ones4;
#pragma unroll
  for (int e = 0; e < 4; ++e) ones4[e] = (short)0x3F80;  // bf16 1.0

  f32x4 O[2][4] = {};
  f32x4 Lacc[2] = {{0.f,0.f,0.f,0.f},{0.f,0.f,0.f,0.f}};

  const short* kb  = k + ((long)b * SEQ) * DM + h * DKH;
  const short* vtb = vt + (long)bh * (DKH * SEQ);
  const int lrow8 = lane >> 3;
  const int lcolsw = (((lane & 7) ^ lrow8) & 7) * 8;   // 16B XOR swizzle

// stage tile KT into buffer BSEL — v8's linear staging
#define STAGE(KT, BSEL) do{                                                     \
  _Pragma("unroll")                                                             \
  for (int i_ = 0; i_ < 2; ++i_){                                               \
    int jj_ = w * 2 + i_;                                                       \
    GLOAD16(kb + ((KT) * 64 + jj_ * 8 + lrow8) * DM + lcolsw,                   \
            &Ks[BSEL][jj_ * 512]);                                              \
    GLOAD16(vtb + (jj_ * 8 + lrow8) * SEQ + (KT) * 64 + lcolsw,                 \
            &Vs[BSEL][jj_ * 512]);                                              \
  } }while(0)

// v8 compute body verbatim, parameterized only by buffer index
#define COMPUTE(BS) do{                                                         \
  __builtin_amdgcn_s_setprio(1);                                                \
  f32x4 scT[2][4];                                                              \
  _Pragma("unroll") for (int mt = 0; mt < 2; ++mt)                              \
    _Pragma("unroll") for (int nt = 0; nt < 4; ++nt)                            \
      scT[mt][nt] = (f32x4){0.f, 0.f, 0.f, 0.f};                                \
  _Pragma("unroll") for (int ks = 0; ks < 2; ++ks){                             \
    _Pragma("unroll") for (int nt = 0; nt < 4; ++nt){                           \
      frag8 ak = *(const frag8*)&Ks[BS][(nt * 16 + l15) * 64 +                  \
                                        (((ks * 4 + quad) ^ (l15 & 7)) * 8)];   \
      _Pragma("unroll") for (int mt = 0; mt < 2; ++mt)                          \
        scT[mt][nt] = __builtin_amdgcn_mfma_f32_16x16x32_bf16(                  \
            ak, aq[mt][ks], scT[mt][nt], 0, 0, 0);                              \
    }                                                                           \
  }                                                                             \
  frag4 ap[2][4];                                                               \
  _Pragma("unroll") for (int mt = 0; mt < 2; ++mt)                              \
    _Pragma("unroll") for (int nt = 0; nt < 4; ++nt){                           \
      _Pragma("unroll") for (int r = 0; r < 4; ++r){                            \
        float e = dev_exp2(scT[mt][nt][r]);                                     \
        ap[mt][nt][r] = (short)((__float_as_uint(e) + 0x8000u) >> 16);          \
      }                                                                         \
    }                                                                           \
  _Pragma("unroll") for (int nt = 0; nt < 4; ++nt){                             \
    _Pragma("unroll") for (int dt = 0; dt < 4; ++dt){                           \
      frag4 bv4 = *(const frag4*)&Vs[BS][(dt * 16 + l15) * 64 +                 \
                                   (((nt * 2 + (quad >> 1)) ^ (l15 & 7)) * 8) + \
                                   (quad & 1) * 4];                             \
      _Pragma("unroll") for (int mt = 0; mt < 2; ++mt)                          \
        O[mt][dt] = __builtin_amdgcn_mfma_f32_16x16x16bf16_1k(                  \
            ap[mt][nt], bv4, O[mt][dt], 0, 0, 0);                               \
    }                                                                           \
    _Pragma("unroll") for (int mt = 0; mt < 2; ++mt)                            \
      Lacc[mt] = __builtin_amdgcn_mfma_f32_16x16x16bf16_1k(                     \
          ap[mt][nt], ones4, Lacc[mt], 0, 0, 0);                                \
  }                                                                             \
  __builtin_amdgcn_s_setprio(0);                                                \
}while(0)

// one pipelined iteration: stage KT+2, wait for tile KT (vmcnt(8): leaves the
// 8 loads of tiles KT+1/KT+2 in flight), barrier (publish ALL waves' tile KT),
// fence (no read-hoist above barrier), compute, lgkm-drain + barrier (publish
// "done reading" before a later iter overwrites this buffer)
#define ITER(KT, BC, BSNEXT) do{                                                \
  STAGE((KT) + 2, BSNEXT);                                                      \
  asm volatile("s_waitcnt vmcnt(8)" ::: "memory");                              \
  __builtin_amdgcn_s_barrier();                                                 \
  LDSFENCE();                                                                   \
  COMPUTE(BC);                                                                  \
  asm volatile("s_waitcnt lgkmcnt(0)" ::: "memory");                            \
  __builtin_amdgcn_sched_barrier(0);                                            \
  __builtin_amdgcn_s_barrier();                                                 \
}while(0)

  STAGE(0, 0);
  STAGE(1, 1);
  for (int kt = 0; kt < SEQ / 64 - 2; kt += 3){   // 30 iterations, tiles 0..29
    ITER(kt,     0, 2);
    ITER(kt + 1, 1, 0);
    ITER(kt + 2, 2, 1);
  }
  // epilogue: tiles 30 (buf 0) and 31 (buf 1), no further staging
  asm volatile("s_waitcnt vmcnt(4)" ::: "memory");
  __builtin_amdgcn_s_barrier();
  LDSFENCE();
  COMPUTE(0);
  asm volatile("s_waitcnt vmcnt(0)" ::: "memory");
  __builtin_amdgcn_s_barrier();
  LDSFENCE();
  COMPUTE(1);

#undef ITER
#undef COMPUTE
#undef STAGE

  // epilogue: O/l -> comb bf16  (C-layout: row m=quad*4+r = qrow, col n=l15 = d)
  short* ob = comb + ((long)(b * SEQ + q0 + w * 32)) * DM + h * DKH;
#pragma unroll
  for (int mt = 0; mt < 2; ++mt){
#pragma unroll
    for (int r = 0; r < 4; ++r){
      float inv = 1.f / Lacc[mt][r];
#pragma unroll
      for (int nt = 0; nt < 4; ++nt)
        ob[(mt * 16 + quad * 4 + r) * DM + nt * 16 + l15] = (short)f2bf(O[mt][nt][r] * inv);
    }
  }
}

// ---------------- launch ----------------
extern "C" void kernel_launch(void* const* d_in, const int* in_sizes, int n_in,
                              void* d_out, int out_size, void* d_ws, size_t ws_size,
                              hipStream_t stream){
  const float* Q  = (const float*)d_in[0];
  const float* K  = (const float*)d_in[1];
  const float* V  = (const float*)d_in[2];
  const float* Wq = (const float*)d_in[3];
  const float* bq = (const float*)d_in[4];
  const float* Wk = (const float*)d_in[5];
  const float* bk = (const float*)d_in[6];
  const float* Wv = (const float*)d_in[7];
  const float* bv = (const float*)d_in[8];
  const float* Wo = (const float*)d_in[9];
  const float* bo = (const float*)d_in[10];
  float* out = (float*)d_out;

  const long TEN = (long)NB * SEQ * DM;   // 4194304 elements per activation tensor
  const long WEL = (long)DM * DM;         // 1048576 per weight
  short* ws   = (short*)d_ws;
  short* xc   = ws;                 // 3 * TEN
  short* wt   = xc + 3 * TEN;       // 4 * WEL
  short* qkv  = wt + 4 * WEL;       // 3 * TEN   (q, k, v projections, bf16)
  short* vtr  = qkv + 3 * TEN;      // TEN       (B,H,Dk,S)
  short* comb = vtr + TEN;          // TEN

  cast_qkv<<<dim3(4096, 1, 3), 256, 0, stream>>>(Q, K, V, xc);
  wtrans<<<dim3(32, 32, 4), 256, 0, stream>>>(Wq, Wk, Wv, Wo, wt);
  // projections: z=0 -> q (scaled by log2e/sqrt(Dk) for exp2 softmax), z=1 -> k, z=2 -> v
  gemm_bt<short><<<dim3(32, 8, 3), 256, 0, stream>>>(xc, TEN, wt, WEL, bq, bk, bv,
                                                     qkv, TEN, 0.125f * 1.44269504f);
  vtrans<<<dim3(32, 32), 256, 0, stream>>>(qkv + 2 * TEN, vtr);
  flash<<<dim3(16, 32), 256, 0, stream>>>(qkv, qkv + TEN, vtr, comb);
  gemm64_bt<float><<<dim3(64, 8), 256, 0, stream>>>(comb, wt + 3 * WEL, bo, out, 1.0f);
  (void)in_sizes; (void)n_in; (void)out_size; (void)ws_size;
}

// Round 5
// 233.728 us; speedup vs baseline: 1.0413x; 1.0075x over previous
//
#include <hip/hip_runtime.h>
#include <stdint.h>

#define DM   1024
#define NH   16
#define DKH  64
#define SEQ  2048
#define NB   2

typedef __attribute__((ext_vector_type(8))) short  frag8;
typedef __attribute__((ext_vector_type(4))) short  frag4;
typedef __attribute__((ext_vector_type(4))) short  short4v;
typedef __attribute__((ext_vector_type(8))) short  short8v;
typedef __attribute__((ext_vector_type(4))) float  f32x4;

__device__ __forceinline__ unsigned short f2bf(float x){
  unsigned u = __float_as_uint(x);
  u += 0x7fffu + ((u >> 16) & 1u);
  return (unsigned short)(u >> 16);
}

// exp2 via the raw intrinsic (v_exp_f32) — avoids glibc __exp2f macro collision
__device__ __forceinline__ float dev_exp2(float x){
  return __builtin_amdgcn_exp2f(x);
}

#define GLOAD16(GP, LP) __builtin_amdgcn_global_load_lds( \
    (__attribute__((address_space(1))) void*)(GP), \
    (__attribute__((address_space(3))) void*)(LP), 16, 0, 0)

// Compiler memory fence (zero instructions): raw s_barrier is NOT an LLVM memory
// fence, so dependent LDS reads can be hoisted above it. Pin them below.
#define LDSFENCE() do{ asm volatile("" ::: "memory"); \
                       __builtin_amdgcn_sched_barrier(0); }while(0)

// NOTE (bisect r0-r4): v_cvt_pk_bf16_f32 inline-asm pack FAILED 3/3 attempts
// (0.06 / 0.06 / NaN) while the manual add+shift pack passed 2/2. Do NOT
// reintroduce cvt_pk here without an isolated hardware probe of its semantics.

// 16B XOR swizzle: LDS granule g of row r holds global granule g^(r&7);
// staging loads global granule (lane&7)^row. (R4: conflicts -> 0 on b128 reads.)

// ---------------- cast fp32 -> bf16 for Q,K,V ----------------
__global__ __launch_bounds__(256) void cast_qkv(const float* __restrict__ Q,
                                                const float* __restrict__ K,
                                                const float* __restrict__ V,
                                                short* __restrict__ dst){
  const int z = blockIdx.z;
  const float* src = (z == 0) ? Q : (z == 1 ? K : V);
  const int i = (blockIdx.x * 256 + threadIdx.x) * 4;
  float4 f = *(const float4*)(src + i);
  short4v s;
  s.x = (short)f2bf(f.x); s.y = (short)f2bf(f.y);
  s.z = (short)f2bf(f.z); s.w = (short)f2bf(f.w);
  *(short4v*)(dst + (long)z * (SEQ*NB*DM) + i) = s;
}

// ---------------- weight transpose + cast: W(K,N) -> Wt(N,K) bf16 ----------------
__global__ __launch_bounds__(256) void wtrans(const float* __restrict__ Wq,
                                              const float* __restrict__ Wk,
                                              const float* __restrict__ Wv,
                                              const float* __restrict__ Wo,
                                              short* __restrict__ wt){
  const int z = blockIdx.z;
  const float* W = (z == 0) ? Wq : (z == 1 ? Wk : (z == 2 ? Wv : Wo));
  short* out = wt + (long)z * (DM*DM);
  __shared__ float t[32][33];
  const int n0 = blockIdx.x * 32, k0 = blockIdx.y * 32;
  const int c = threadIdx.x & 31, r0 = threadIdx.x >> 5;
#pragma unroll
  for (int i = 0; i < 4; ++i){
    int r = r0 + i * 8;
    t[r][c] = W[(k0 + r) * DM + n0 + c];
  }
  __syncthreads();
#pragma unroll
  for (int i = 0; i < 4; ++i){
    int r = r0 + i * 8;
    out[(n0 + r) * DM + k0 + c] = (short)f2bf(t[c][r]);
  }
}

// ---------------- 128x128 bf16 MFMA GEMM: C = A(M,K) * Bt(N,K)^T, +bias, *scale ----
// 2-buffer LDS + counted vmcnt pipeline (the discipline proven in flash v11):
// STAGE(t+1) -> vmcnt(8) -> barrier -> fence -> COMPUTE(t) -> lgkmcnt(0) -> barrier.
__device__ __forceinline__ void store_out(short* p, float v){ *p = (short)f2bf(v); }
__device__ __forceinline__ void store_out(float* p, float v){ *p = v; }

template<typename OT>
__global__ __launch_bounds__(256) void gemm_bt(const short* __restrict__ Abase, long Astride,
                                               const short* __restrict__ Btbase, long Btstride,
                                               const float* __restrict__ bias0,
                                               const float* __restrict__ bias1,
                                               const float* __restrict__ bias2,
                                               OT* __restrict__ Cbase, long Cstride,
                                               float qscale){
  const int z = blockIdx.z;
  const short* A  = Abase + (long)z * Astride;
  const short* Bt = Btbase + (long)z * Btstride;
  OT* C = Cbase + (long)z * Cstride;
  const float* bias = (z == 0) ? bias0 : (z == 1 ? bias1 : bias2);
  const float scale = (z == 0) ? qscale : 1.0f;
  const int KD = DM, ND = DM;

  __shared__ __align__(16) short As[2][128 * 64];
  __shared__ __align__(16) short Bs[2][128 * 64];

  const int tid = threadIdx.x;
  const int w = tid >> 6, lane = tid & 63, l15 = lane & 15, quad = lane >> 4;
  const int wy = w >> 1, wx = w & 1;
  const int bm = blockIdx.x * 128, bn = blockIdx.y * 128;
  const int lrow = lane >> 3;
  const int lcolsw = (((lane & 7) ^ lrow) & 7) * 8;   // swizzled source granule

  f32x4 acc[4][4] = {};

#define GSTAGE(KT, BSEL) do{                                                    \
  _Pragma("unroll")                                                             \
  for (int i_ = 0; i_ < 4; ++i_){                                               \
    int j_ = w * 4 + i_;                                                        \
    GLOAD16(A  + (bm + j_ * 8 + lrow) * KD + (KT) * 64 + lcolsw,                \
            &As[BSEL][j_ * 512]);                                               \
    GLOAD16(Bt + (bn + j_ * 8 + lrow) * KD + (KT) * 64 + lcolsw,                \
            &Bs[BSEL][j_ * 512]);                                               \
  } }while(0)

#define GCOMPUTE(BS) do{                                                        \
  _Pragma("unroll") for (int ks = 0; ks < 2; ++ks){                             \
    frag8 af[4], bf_[4];                                                        \
    _Pragma("unroll") for (int mt = 0; mt < 4; ++mt)                            \
      af[mt] = *(const frag8*)&As[BS][(wy * 64 + mt * 16 + l15) * 64 +          \
                                      (((ks * 4 + quad) ^ (l15 & 7)) * 8)];     \
    _Pragma("unroll") for (int nt = 0; nt < 4; ++nt)                            \
      bf_[nt] = *(const frag8*)&Bs[BS][(wx * 64 + nt * 16 + l15) * 64 +         \
                                       (((ks * 4 + quad) ^ (l15 & 7)) * 8)];    \
    _Pragma("unroll") for (int mt = 0; mt < 4; ++mt)                            \
      _Pragma("unroll") for (int nt = 0; nt < 4; ++nt)                          \
        acc[mt][nt] = __builtin_amdgcn_mfma_f32_16x16x32_bf16(                  \
            af[mt], bf_[nt], acc[mt][nt], 0, 0, 0);                             \
  } }while(0)

  GSTAGE(0, 0);
  for (int t = 0; t < KD / 64 - 1; ++t){       // 15 pipelined iterations
    GSTAGE(t + 1, (t + 1) & 1);
    asm volatile("s_waitcnt vmcnt(8)" ::: "memory");
    __builtin_amdgcn_s_barrier();
    LDSFENCE();
    GCOMPUTE(t & 1);
    asm volatile("s_waitcnt lgkmcnt(0)" ::: "memory");
    __builtin_amdgcn_sched_barrier(0);
    __builtin_amdgcn_s_barrier();
  }
  asm volatile("s_waitcnt vmcnt(0)" ::: "memory");
  __builtin_amdgcn_s_barrier();
  LDSFENCE();
  GCOMPUTE(1);                                  // tile 15 (odd)

#undef GSTAGE
#undef GCOMPUTE

#pragma unroll
  for (int mt = 0; mt < 4; ++mt){
#pragma unroll
    for (int r = 0; r < 4; ++r){
      int m = bm + wy * 64 + mt * 16 + quad * 4 + r;
#pragma unroll
      for (int nt = 0; nt < 4; ++nt){
        int n = bn + wx * 64 + nt * 16 + l15;
        float v = (acc[mt][nt][r] + bias[n]) * scale;
        store_out(&C[(long)m * ND + n], v);
      }
    }
  }
}

// ---------------- 64x128-tile GEMM (for low-block-count output projection) -------
// same 2-buffer counted-vmcnt pipeline (6 loads/tile -> vmcnt(6)).
template<typename OT>
__global__ __launch_bounds__(256) void gemm64_bt(const short* __restrict__ A,
                                                 const short* __restrict__ Bt,
                                                 const float* __restrict__ bias,
                                                 OT* __restrict__ C,
                                                 float scale){
  const int KD = DM, ND = DM;
  __shared__ __align__(16) short As[2][64 * 64];
  __shared__ __align__(16) short Bs[2][128 * 64];
  const int tid = threadIdx.x;
  const int w = tid >> 6, lane = tid & 63, l15 = lane & 15, quad = lane >> 4;
  const int wy = w >> 1, wx = w & 1;
  const int bm = blockIdx.x * 64, bn = blockIdx.y * 128;
  const int lrow = lane >> 3;
  const int lcolsw = (((lane & 7) ^ lrow) & 7) * 8;
  f32x4 acc[2][4] = {};

#define GSTAGE64(KT, BSEL) do{                                                  \
  _Pragma("unroll")                                                             \
  for (int i_ = 0; i_ < 2; ++i_){                                               \
    int j_ = w * 2 + i_;                                                        \
    GLOAD16(A + (bm + j_ * 8 + lrow) * KD + (KT) * 64 + lcolsw,                 \
            &As[BSEL][j_ * 512]);                                               \
  }                                                                             \
  _Pragma("unroll")                                                             \
  for (int i_ = 0; i_ < 4; ++i_){                                               \
    int j_ = w * 4 + i_;                                                        \
    GLOAD16(Bt + (bn + j_ * 8 + lrow) * KD + (KT) * 64 + lcolsw,                \
            &Bs[BSEL][j_ * 512]);                                               \
  } }while(0)

#define GCOMPUTE64(BS) do{                                                      \
  _Pragma("unroll") for (int ks = 0; ks < 2; ++ks){                             \
    frag8 af[2], bf_[4];                                                        \
    _Pragma("unroll") for (int mt = 0; mt < 2; ++mt)                            \
      af[mt] = *(const frag8*)&As[BS][(wy * 32 + mt * 16 + l15) * 64 +          \
                                      (((ks * 4 + quad) ^ (l15 & 7)) * 8)];     \
    _Pragma("unroll") for (int nt = 0; nt < 4; ++nt)                            \
      bf_[nt] = *(const frag8*)&Bs[BS][(wx * 64 + nt * 16 + l15) * 64 +         \
                                       (((ks * 4 + quad) ^ (l15 & 7)) * 8)];    \
    _Pragma("unroll") for (int mt = 0; mt < 2; ++mt)                            \
      _Pragma("unroll") for (int nt = 0; nt < 4; ++nt)                          \
        acc[mt][nt] = __builtin_amdgcn_mfma_f32_16x16x32_bf16(                  \
            af[mt], bf_[nt], acc[mt][nt], 0, 0, 0);                             \
  } }while(0)

  GSTAGE64(0, 0);
  for (int t = 0; t < KD / 64 - 1; ++t){
    GSTAGE64(t + 1, (t + 1) & 1);
    asm volatile("s_waitcnt vmcnt(6)" ::: "memory");
    __builtin_amdgcn_s_barrier();
    LDSFENCE();
    GCOMPUTE64(t & 1);
    asm volatile("s_waitcnt lgkmcnt(0)" ::: "memory");
    __builtin_amdgcn_sched_barrier(0);
    __builtin_amdgcn_s_barrier();
  }
  asm volatile("s_waitcnt vmcnt(0)" ::: "memory");
  __builtin_amdgcn_s_barrier();
  LDSFENCE();
  GCOMPUTE64(1);

#undef GSTAGE64
#undef GCOMPUTE64

#pragma unroll
  for (int mt = 0; mt < 2; ++mt){
#pragma unroll
    for (int r = 0; r < 4; ++r){
      int m = bm + wy * 32 + mt * 16 + quad * 4 + r;
#pragma unroll
      for (int nt = 0; nt < 4; ++nt){
        int n = bn + wx * 64 + nt * 16 + l15;
        store_out(&C[(long)m * ND + n], (acc[mt][nt][r] + bias[n]) * scale);
      }
    }
  }
}

// ---------------- v (B*S, DM) -> vt (B,H,Dk,S) bf16 transpose ----------------
__global__ __launch_bounds__(256) void vtrans(const short* __restrict__ v,
                                              short* __restrict__ vt){
  const int bh = blockIdx.y;       // b*16+h
  const int b = bh >> 4, h = bh & 15;
  const int s0 = blockIdx.x * 64;
  __shared__ short tT[64][66];
  const short* vb = v + ((long)(b * SEQ + s0)) * DM + h * DKH;
  for (int j = threadIdx.x; j < 512; j += 256){
    int row = j >> 3, off = (j & 7) * 8;
    short8v d = *(const short8v*)(vb + row * DM + off);
#pragma unroll
    for (int e = 0; e < 8; ++e) tT[off + e][row] = d[e];
  }
  __syncthreads();
  short* out = vt + (long)bh * (DKH * SEQ) + s0;
  for (int j = threadIdx.x; j < 512; j += 256){
    int dr = j >> 3, soff = (j & 7) * 8;
    short8v o;
#pragma unroll
    for (int e = 0; e < 8; ++e) o[e] = tT[dr][soff + e];
    *(short8v*)(out + dr * SEQ + soff) = o;
  }
}

// ---------------- flash attention v13 = v11 VERBATIM ------------------------------
// (v8 compute: linear K staging, K=16 _1k PV, MANUAL bf16 pack, ones4-L;
//  3-buffer LDS, depth-2 prefetch, counted vmcnt(8), LDSFENCE discipline.)
// Passed round 3 at 62.3us / absmax 1.45e-3.
__global__ __launch_bounds__(256) void flash(const short* __restrict__ q,
                                             const short* __restrict__ k,
                                             const short* __restrict__ vt,
                                             short* __restrict__ comb){
  const int bh = blockIdx.y;
  const int b = bh >> 4, h = bh & 15;
  const int q0 = blockIdx.x * 128;         // 128 Q-rows per block, 32 per wave
  const int tid = threadIdx.x;
  const int w = tid >> 6, lane = tid & 63, l15 = lane & 15, quad = lane >> 4;

  __shared__ __align__(16) short Ks[3][64 * 64];
  __shared__ __align__(16) short Vs[3][64 * 64];

  // preload Q fragments straight from global (used as MFMA B operand)
  frag8 aq[2][2];
  const short* qb = q + ((long)(b * SEQ + q0 + w * 32)) * DM + h * DKH;
#pragma unroll
  for (int mt = 0; mt < 2; ++mt)
#pragma unroll
    for (int ks = 0; ks < 2; ++ks)
      aq[mt][ks] = *(const frag8*)(qb + (mt * 16 + l15) * DM + ks * 32 + quad * 8);

  frag4 ones4;
#pragma unroll
  for (int e = 0; e < 4; ++e) ones4[e] = (short)0x3F80;  // bf16 1.0

  f32x4 O[2][4] = {};
  f32x4 Lacc[2] = {{0.f,0.f,0.f,0.f},{0.f,0.f,0.f,0.f}};

  const short* kb  = k + ((long)b * SEQ) * DM + h * DKH;
  const short* vtb = vt + (long)bh * (DKH * SEQ);
  const int lrow8 = lane >> 3;
  const int lcolsw = (((lane & 7) ^ lrow8) & 7) * 8;   // 16B XOR swizzle

// stage tile KT into buffer BSEL — v8's linear staging
#define STAGE(KT, BSEL) do{                                                     \
  _Pragma("unroll")                                                             \
  for (int i_ = 0; i_ < 2; ++i_){                                               \
    int jj_ = w * 2 + i_;                                                       \
    GLOAD16(kb + ((KT) * 64 + jj_ * 8 + lrow8) * DM + lcolsw,                   \
            &Ks[BSEL][jj_ * 512]);                                              \
    GLOAD16(vtb + (jj_ * 8 + lrow8) * SEQ + (KT) * 64 + lcolsw,                 \
            &Vs[BSEL][jj_ * 512]);                                              \
  } }while(0)

// v8 compute body verbatim, parameterized only by buffer index
#define COMPUTE(BS) do{                                                         \
  __builtin_amdgcn_s_setprio(1);                                                \
  f32x4 scT[2][4];                                                              \
  _Pragma("unroll") for (int mt = 0; mt < 2; ++mt)                              \
    _Pragma("unroll") for (int nt = 0; nt < 4; ++nt)                            \
      scT[mt][nt] = (f32x4){0.f, 0.f, 0.f, 0.f};                                \
  _Pragma("unroll") for (int ks = 0; ks < 2; ++ks){                             \
    _Pragma("unroll") for (int nt = 0; nt < 4; ++nt){                           \
      frag8 ak = *(const frag8*)&Ks[BS][(nt * 16 + l15) * 64 +                  \
                                        (((ks * 4 + quad) ^ (l15 & 7)) * 8)];   \
      _Pragma("unroll") for (int mt = 0; mt < 2; ++mt)                          \
        scT[mt][nt] = __builtin_amdgcn_mfma_f32_16x16x32_bf16(                  \
            ak, aq[mt][ks], scT[mt][nt], 0, 0, 0);                              \
    }                                                                           \
  }                                                                             \
  frag4 ap[2][4];                                                               \
  _Pragma("unroll") for (int mt = 0; mt < 2; ++mt)                              \
    _Pragma("unroll") for (int nt = 0; nt < 4; ++nt){                           \
      _Pragma("unroll") for (int r = 0; r < 4; ++r){                            \
        float e = dev_exp2(scT[mt][nt][r]);                                     \
        ap[mt][nt][r] = (short)((__float_as_uint(e) + 0x8000u) >> 16);          \
      }                                                                         \
    }                                                                           \
  _Pragma("unroll") for (int nt = 0; nt < 4; ++nt){                             \
    _Pragma("unroll") for (int dt = 0; dt < 4; ++dt){                           \
      frag4 bv4 = *(const frag4*)&Vs[BS][(dt * 16 + l15) * 64 +                 \
                                   (((nt * 2 + (quad >> 1)) ^ (l15 & 7)) * 8) + \
                                   (quad & 1) * 4];                             \
      _Pragma("unroll") for (int mt = 0; mt < 2; ++mt)                          \
        O[mt][dt] = __builtin_amdgcn_mfma_f32_16x16x16bf16_1k(                  \
            ap[mt][nt], bv4, O[mt][dt], 0, 0, 0);                               \
    }                                                                           \
    _Pragma("unroll") for (int mt = 0; mt < 2; ++mt)                            \
      Lacc[mt] = __builtin_amdgcn_mfma_f32_16x16x16bf16_1k(                     \
          ap[mt][nt], ones4, Lacc[mt], 0, 0, 0);                                \
  }                                                                             \
  __builtin_amdgcn_s_setprio(0);                                                \
}while(0)

// one pipelined iteration: stage KT+2, wait for tile KT (vmcnt(8): leaves the
// 8 loads of tiles KT+1/KT+2 in flight), barrier (publish ALL waves' tile KT),
// fence (no read-hoist above barrier), compute, lgkm-drain + barrier (publish
// "done reading" before a later iter overwrites this buffer)
#define ITER(KT, BC, BSNEXT) do{                                                \
  STAGE((KT) + 2, BSNEXT);                                                      \
  asm volatile("s_waitcnt vmcnt(8)" ::: "memory");                              \
  __builtin_amdgcn_s_barrier();                                                 \
  LDSFENCE();                                                                   \
  COMPUTE(BC);                                                                  \
  asm volatile("s_waitcnt lgkmcnt(0)" ::: "memory");                            \
  __builtin_amdgcn_sched_barrier(0);                                            \
  __builtin_amdgcn_s_barrier();                                                 \
}while(0)

  STAGE(0, 0);
  STAGE(1, 1);
  for (int kt = 0; kt < SEQ / 64 - 2; kt += 3){   // 30 iterations, tiles 0..29
    ITER(kt,     0, 2);
    ITER(kt + 1, 1, 0);
    ITER(kt + 2, 2, 1);
  }
  // epilogue: tiles 30 (buf 0) and 31 (buf 1), no further staging
  asm volatile("s_waitcnt vmcnt(4)" ::: "memory");
  __builtin_amdgcn_s_barrier();
  LDSFENCE();
  COMPUTE(0);
  asm volatile("s_waitcnt vmcnt(0)" ::: "memory");
  __builtin_amdgcn_s_barrier();
  LDSFENCE();
  COMPUTE(1);

#undef ITER
#undef COMPUTE
#undef STAGE

  // epilogue: O/l -> comb bf16  (C-layout: row m=quad*4+r = qrow, col n=l15 = d)
  short* ob = comb + ((long)(b * SEQ + q0 + w * 32)) * DM + h * DKH;
#pragma unroll
  for (int mt = 0; mt < 2; ++mt){
#pragma unroll
    for (int r = 0; r < 4; ++r){
      float inv = 1.f / Lacc[mt][r];
#pragma unroll
      for (int nt = 0; nt < 4; ++nt)
        ob[(mt * 16 + quad * 4 + r) * DM + nt * 16 + l15] = (short)f2bf(O[mt][nt][r] * inv);
    }
  }
}

// ---------------- launch ----------------
extern "C" void kernel_launch(void* const* d_in, const int* in_sizes, int n_in,
                              void* d_out, int out_size, void* d_ws, size_t ws_size,
                              hipStream_t stream){
  const float* Q  = (const float*)d_in[0];
  const float* K  = (const float*)d_in[1];
  const float* V  = (const float*)d_in[2];
  const float* Wq = (const float*)d_in[3];
  const float* bq = (const float*)d_in[4];
  const float* Wk = (const float*)d_in[5];
  const float* bk = (const float*)d_in[6];
  const float* Wv = (const float*)d_in[7];
  const float* bv = (const float*)d_in[8];
  const float* Wo = (const float*)d_in[9];
  const float* bo = (const float*)d_in[10];
  float* out = (float*)d_out;

  const long TEN = (long)NB * SEQ * DM;   // 4194304 elements per activation tensor
  const long WEL = (long)DM * DM;         // 1048576 per weight
  short* ws   = (short*)d_ws;
  short* xc   = ws;                 // 3 * TEN
  short* wt   = xc + 3 * TEN;       // 4 * WEL
  short* qkv  = wt + 4 * WEL;       // 3 * TEN   (q, k, v projections, bf16)
  short* vtr  = qkv + 3 * TEN;      // TEN       (B,H,Dk,S)
  short* comb = vtr + TEN;          // TEN

  cast_qkv<<<dim3(4096, 1, 3), 256, 0, stream>>>(Q, K, V, xc);
  wtrans<<<dim3(32, 32, 4), 256, 0, stream>>>(Wq, Wk, Wv, Wo, wt);
  // projections: z=0 -> q (scaled by log2e/sqrt(Dk) for exp2 softmax), z=1 -> k, z=2 -> v
  gemm_bt<short><<<dim3(32, 8, 3), 256, 0, stream>>>(xc, TEN, wt, WEL, bq, bk, bv,
                                                     qkv, TEN, 0.125f * 1.44269504f);
  vtrans<<<dim3(32, 32), 256, 0, stream>>>(qkv + 2 * TEN, vtr);
  flash<<<dim3(16, 32), 256, 0, stream>>>(qkv, qkv + TEN, vtr, comb);
  gemm64_bt<float><<<dim3(64, 8), 256, 0, stream>>>(comb, wt + 3 * WEL, bo, out, 1.0f);
  (void)in_sizes; (void)n_in; (void)out_size; (void)ws_size;
}

// Round 6
// 224.329 us; speedup vs baseline: 1.0849x; 1.0419x over previous
//
#include <hip/hip_runtime.h>
#include <stdint.h>

#define DM   1024
#define NH   16
#define DKH  64
#define SEQ  2048
#define NB   2

typedef __attribute__((ext_vector_type(8))) short  frag8;
typedef __attribute__((ext_vector_type(4))) short  frag4;
typedef __attribute__((ext_vector_type(4))) short  short4v;
typedef __attribute__((ext_vector_type(8))) short  short8v;
typedef __attribute__((ext_vector_type(4))) float  f32x4;

__device__ __forceinline__ unsigned short f2bf(float x){
  unsigned u = __float_as_uint(x);
  u += 0x7fffu + ((u >> 16) & 1u);
  return (unsigned short)(u >> 16);
}

// exp2 via the raw intrinsic (v_exp_f32) — avoids glibc __exp2f macro collision
__device__ __forceinline__ float dev_exp2(float x){
  return __builtin_amdgcn_exp2f(x);
}

#define GLOAD16(GP, LP) __builtin_amdgcn_global_load_lds( \
    (__attribute__((address_space(1))) void*)(GP), \
    (__attribute__((address_space(3))) void*)(LP), 16, 0, 0)

// Compiler memory fence (zero instructions): raw s_barrier is NOT an LLVM memory
// fence, so dependent LDS reads can be hoisted above it. Pin them below.
#define LDSFENCE() do{ asm volatile("" ::: "memory"); \
                       __builtin_amdgcn_sched_barrier(0); }while(0)

// NOTE (bisect r0-r5): v_cvt_pk_bf16_f32 inline-asm pack FAILED 3/3 attempts
// (0.06 / 0.06 / NaN) while the manual add+shift pack passed 3/3. Do NOT
// reintroduce cvt_pk without an isolated hardware probe of its semantics.

// 16B XOR swizzle: LDS granule g of row r holds global granule g^(r&7);
// staging loads global granule (lane&7)^row. (R4: conflicts -> 0 on b128 reads.)

// ---------------- cast fp32 -> bf16 for Q,K,V ----------------
__global__ __launch_bounds__(256) void cast_qkv(const float* __restrict__ Q,
                                                const float* __restrict__ K,
                                                const float* __restrict__ V,
                                                short* __restrict__ dst){
  const int z = blockIdx.z;
  const float* src = (z == 0) ? Q : (z == 1 ? K : V);
  const int i = (blockIdx.x * 256 + threadIdx.x) * 4;
  float4 f = *(const float4*)(src + i);
  short4v s;
  s.x = (short)f2bf(f.x); s.y = (short)f2bf(f.y);
  s.z = (short)f2bf(f.z); s.w = (short)f2bf(f.w);
  *(short4v*)(dst + (long)z * (SEQ*NB*DM) + i) = s;
}

// ---------------- weight transpose + cast: W(K,N) -> Wt(N,K) bf16 ----------------
__global__ __launch_bounds__(256) void wtrans(const float* __restrict__ Wq,
                                              const float* __restrict__ Wk,
                                              const float* __restrict__ Wv,
                                              const float* __restrict__ Wo,
                                              short* __restrict__ wt){
  const int z = blockIdx.z;
  const float* W = (z == 0) ? Wq : (z == 1 ? Wk : (z == 2 ? Wv : Wo));
  short* out = wt + (long)z * (DM*DM);
  __shared__ float t[32][33];
  const int n0 = blockIdx.x * 32, k0 = blockIdx.y * 32;
  const int c = threadIdx.x & 31, r0 = threadIdx.x >> 5;
#pragma unroll
  for (int i = 0; i < 4; ++i){
    int r = r0 + i * 8;
    t[r][c] = W[(k0 + r) * DM + n0 + c];
  }
  __syncthreads();
#pragma unroll
  for (int i = 0; i < 4; ++i){
    int r = r0 + i * 8;
    out[(n0 + r) * DM + k0 + c] = (short)f2bf(t[c][r]);
  }
}

// ---------------- 128x128 bf16 MFMA GEMM: C = A(M,K) * Bt(N,K)^T, +bias, *scale ----
// 2-buffer LDS + counted vmcnt pipeline (proven r5):
// STAGE(t+1) -> vmcnt(8) -> barrier -> fence -> COMPUTE(t) -> lgkmcnt(0) -> barrier.
__device__ __forceinline__ void store_out(short* p, float v){ *p = (short)f2bf(v); }
__device__ __forceinline__ void store_out(float* p, float v){ *p = v; }

template<typename OT>
__global__ __launch_bounds__(256) void gemm_bt(const short* __restrict__ Abase, long Astride,
                                               const short* __restrict__ Btbase, long Btstride,
                                               const float* __restrict__ bias0,
                                               const float* __restrict__ bias1,
                                               const float* __restrict__ bias2,
                                               OT* __restrict__ Cbase, long Cstride,
                                               float qscale){
  const int z = blockIdx.z;
  const short* A  = Abase + (long)z * Astride;
  const short* Bt = Btbase + (long)z * Btstride;
  OT* C = Cbase + (long)z * Cstride;
  const float* bias = (z == 0) ? bias0 : (z == 1 ? bias1 : bias2);
  const float scale = (z == 0) ? qscale : 1.0f;
  const int KD = DM, ND = DM;

  __shared__ __align__(16) short As[2][128 * 64];
  __shared__ __align__(16) short Bs[2][128 * 64];

  const int tid = threadIdx.x;
  const int w = tid >> 6, lane = tid & 63, l15 = lane & 15, quad = lane >> 4;
  const int wy = w >> 1, wx = w & 1;
  const int bm = blockIdx.x * 128, bn = blockIdx.y * 128;
  const int lrow = lane >> 3;
  const int lcolsw = (((lane & 7) ^ lrow) & 7) * 8;   // swizzled source granule

  f32x4 acc[4][4] = {};

#define GSTAGE(KT, BSEL) do{                                                    \
  _Pragma("unroll")                                                             \
  for (int i_ = 0; i_ < 4; ++i_){                                               \
    int j_ = w * 4 + i_;                                                        \
    GLOAD16(A  + (bm + j_ * 8 + lrow) * KD + (KT) * 64 + lcolsw,                \
            &As[BSEL][j_ * 512]);                                               \
    GLOAD16(Bt + (bn + j_ * 8 + lrow) * KD + (KT) * 64 + lcolsw,                \
            &Bs[BSEL][j_ * 512]);                                               \
  } }while(0)

#define GCOMPUTE(BS) do{                                                        \
  _Pragma("unroll") for (int ks = 0; ks < 2; ++ks){                             \
    frag8 af[4], bf_[4];                                                        \
    _Pragma("unroll") for (int mt = 0; mt < 4; ++mt)                            \
      af[mt] = *(const frag8*)&As[BS][(wy * 64 + mt * 16 + l15) * 64 +          \
                                      (((ks * 4 + quad) ^ (l15 & 7)) * 8)];     \
    _Pragma("unroll") for (int nt = 0; nt < 4; ++nt)                            \
      bf_[nt] = *(const frag8*)&Bs[BS][(wx * 64 + nt * 16 + l15) * 64 +         \
                                       (((ks * 4 + quad) ^ (l15 & 7)) * 8)];    \
    _Pragma("unroll") for (int mt = 0; mt < 4; ++mt)                            \
      _Pragma("unroll") for (int nt = 0; nt < 4; ++nt)                          \
        acc[mt][nt] = __builtin_amdgcn_mfma_f32_16x16x32_bf16(                  \
            af[mt], bf_[nt], acc[mt][nt], 0, 0, 0);                             \
  } }while(0)

  GSTAGE(0, 0);
  for (int t = 0; t < KD / 64 - 1; ++t){       // 15 pipelined iterations
    GSTAGE(t + 1, (t + 1) & 1);
    asm volatile("s_waitcnt vmcnt(8)" ::: "memory");
    __builtin_amdgcn_s_barrier();
    LDSFENCE();
    GCOMPUTE(t & 1);
    asm volatile("s_waitcnt lgkmcnt(0)" ::: "memory");
    __builtin_amdgcn_sched_barrier(0);
    __builtin_amdgcn_s_barrier();
  }
  asm volatile("s_waitcnt vmcnt(0)" ::: "memory");
  __builtin_amdgcn_s_barrier();
  LDSFENCE();
  GCOMPUTE(1);                                  // tile 15 (odd)

#undef GSTAGE
#undef GCOMPUTE

#pragma unroll
  for (int mt = 0; mt < 4; ++mt){
#pragma unroll
    for (int r = 0; r < 4; ++r){
      int m = bm + wy * 64 + mt * 16 + quad * 4 + r;
#pragma unroll
      for (int nt = 0; nt < 4; ++nt){
        int n = bn + wx * 64 + nt * 16 + l15;
        float v = (acc[mt][nt][r] + bias[n]) * scale;
        store_out(&C[(long)m * ND + n], v);
      }
    }
  }
}

// ---------------- 64x128-tile GEMM (for low-block-count output projection) -------
// same 2-buffer counted-vmcnt pipeline (6 loads/tile -> vmcnt(6)).
template<typename OT>
__global__ __launch_bounds__(256) void gemm64_bt(const short* __restrict__ A,
                                                 const short* __restrict__ Bt,
                                                 const float* __restrict__ bias,
                                                 OT* __restrict__ C,
                                                 float scale){
  const int KD = DM, ND = DM;
  __shared__ __align__(16) short As[2][64 * 64];
  __shared__ __align__(16) short Bs[2][128 * 64];
  const int tid = threadIdx.x;
  const int w = tid >> 6, lane = tid & 63, l15 = lane & 15, quad = lane >> 4;
  const int wy = w >> 1, wx = w & 1;
  const int bm = blockIdx.x * 64, bn = blockIdx.y * 128;
  const int lrow = lane >> 3;
  const int lcolsw = (((lane & 7) ^ lrow) & 7) * 8;
  f32x4 acc[2][4] = {};

#define GSTAGE64(KT, BSEL) do{                                                  \
  _Pragma("unroll")                                                             \
  for (int i_ = 0; i_ < 2; ++i_){                                               \
    int j_ = w * 2 + i_;                                                        \
    GLOAD16(A + (bm + j_ * 8 + lrow) * KD + (KT) * 64 + lcolsw,                 \
            &As[BSEL][j_ * 512]);                                               \
  }                                                                             \
  _Pragma("unroll")                                                             \
  for (int i_ = 0; i_ < 4; ++i_){                                               \
    int j_ = w * 4 + i_;                                                        \
    GLOAD16(Bt + (bn + j_ * 8 + lrow) * KD + (KT) * 64 + lcolsw,                \
            &Bs[BSEL][j_ * 512]);                                               \
  } }while(0)

#define GCOMPUTE64(BS) do{                                                      \
  _Pragma("unroll") for (int ks = 0; ks < 2; ++ks){                             \
    frag8 af[2], bf_[4];                                                        \
    _Pragma("unroll") for (int mt = 0; mt < 2; ++mt)                            \
      af[mt] = *(const frag8*)&As[BS][(wy * 32 + mt * 16 + l15) * 64 +          \
                                      (((ks * 4 + quad) ^ (l15 & 7)) * 8)];     \
    _Pragma("unroll") for (int nt = 0; nt < 4; ++nt)                            \
      bf_[nt] = *(const frag8*)&Bs[BS][(wx * 64 + nt * 16 + l15) * 64 +         \
                                       (((ks * 4 + quad) ^ (l15 & 7)) * 8)];    \
    _Pragma("unroll") for (int mt = 0; mt < 2; ++mt)                            \
      _Pragma("unroll") for (int nt = 0; nt < 4; ++nt)                          \
        acc[mt][nt] = __builtin_amdgcn_mfma_f32_16x16x32_bf16(                  \
            af[mt], bf_[nt], acc[mt][nt], 0, 0, 0);                             \
  } }while(0)

  GSTAGE64(0, 0);
  for (int t = 0; t < KD / 64 - 1; ++t){
    GSTAGE64(t + 1, (t + 1) & 1);
    asm volatile("s_waitcnt vmcnt(6)" ::: "memory");
    __builtin_amdgcn_s_barrier();
    LDSFENCE();
    GCOMPUTE64(t & 1);
    asm volatile("s_waitcnt lgkmcnt(0)" ::: "memory");
    __builtin_amdgcn_sched_barrier(0);
    __builtin_amdgcn_s_barrier();
  }
  asm volatile("s_waitcnt vmcnt(0)" ::: "memory");
  __builtin_amdgcn_s_barrier();
  LDSFENCE();
  GCOMPUTE64(1);

#undef GSTAGE64
#undef GCOMPUTE64

#pragma unroll
  for (int mt = 0; mt < 2; ++mt){
#pragma unroll
    for (int r = 0; r < 4; ++r){
      int m = bm + wy * 32 + mt * 16 + quad * 4 + r;
#pragma unroll
      for (int nt = 0; nt < 4; ++nt){
        int n = bn + wx * 64 + nt * 16 + l15;
        store_out(&C[(long)m * ND + n], (acc[mt][nt][r] + bias[n]) * scale);
      }
    }
  }
}

// ---------------- v (B*S, DM) -> vt (B,H,Dk,S) bf16 transpose ----------------
__global__ __launch_bounds__(256) void vtrans(const short* __restrict__ v,
                                              short* __restrict__ vt){
  const int bh = blockIdx.y;       // b*16+h
  const int b = bh >> 4, h = bh & 15;
  const int s0 = blockIdx.x * 64;
  __shared__ short tT[64][66];
  const short* vb = v + ((long)(b * SEQ + s0)) * DM + h * DKH;
  for (int j = threadIdx.x; j < 512; j += 256){
    int row = j >> 3, off = (j & 7) * 8;
    short8v d = *(const short8v*)(vb + row * DM + off);
#pragma unroll
    for (int e = 0; e < 8; ++e) tT[off + e][row] = d[e];
  }
  __syncthreads();
  short* out = vt + (long)bh * (DKH * SEQ) + s0;
  for (int j = threadIdx.x; j < 512; j += 256){
    int dr = j >> 3, soff = (j & 7) * 8;
    short8v o;
#pragma unroll
    for (int e = 0; e < 8; ++e) o[e] = tT[dr][soff + e];
    *(short8v*)(out + dr * SEQ + soff) = o;
  }
}

// ---------------- flash attention v14 --------------------------------------------
// v13 (passing, 64us) + the permuted-K K=32 PV, now with the PROVEN manual pack
// (cvt_pk — the convicted v9/v10/v12 bug — is NOT used):
//  * K rows PERMUTED at staging (per-lane global src addr; LDS dest linear):
//    LDS row p holds key a(p) = 32*(p>>5) + 8*((p>>2)&3) + 4*((p>>4)&1) + (p&3).
//    Derivation: scT[mt][2c2+hf][r] (computed in LDS-row space) packs at frag8
//    element hf*4+r; A-operand element (quad,e) must be key c2*32+quad*8+e, i.e.
//    a(32c2+16h+4quad+r) = 32c2+8quad+4h+r — the formula above.
//  * PV + L via mfma_f32_16x16x32_bf16: 16+4 MFMAs/tile instead of 32+8, and the
//    V B-operand is a conflict-free XOR-swizzled ds_read_b128 at granule
//    (c2*4+quad)^(l15&7) of row dt*16+l15 (keys c2*32+quad*8+e, d=dt*16+l15).
//  * QK^T and L are key-permutation-invariant; epilogue unchanged.
__global__ __launch_bounds__(256) void flash(const short* __restrict__ q,
                                             const short* __restrict__ k,
                                             const short* __restrict__ vt,
                                             short* __restrict__ comb){
  const int bh = blockIdx.y;
  const int b = bh >> 4, h = bh & 15;
  const int q0 = blockIdx.x * 128;         // 128 Q-rows per block, 32 per wave
  const int tid = threadIdx.x;
  const int w = tid >> 6, lane = tid & 63, l15 = lane & 15, quad = lane >> 4;

  __shared__ __align__(16) short Ks[3][64 * 64];
  __shared__ __align__(16) short Vs[3][64 * 64];

  // preload Q fragments straight from global (used as MFMA B operand)
  frag8 aq[2][2];
  const short* qb = q + ((long)(b * SEQ + q0 + w * 32)) * DM + h * DKH;
#pragma unroll
  for (int mt = 0; mt < 2; ++mt)
#pragma unroll
    for (int ks = 0; ks < 2; ++ks)
      aq[mt][ks] = *(const frag8*)(qb + (mt * 16 + l15) * DM + ks * 32 + quad * 8);

  frag8 ones8;
#pragma unroll
  for (int e = 0; e < 8; ++e) ones8[e] = (short)0x3F80;  // bf16 1.0

  f32x4 O[2][4] = {};
  f32x4 Lacc[2] = {{0.f,0.f,0.f,0.f},{0.f,0.f,0.f,0.f}};

  const short* kb  = k + ((long)b * SEQ) * DM + h * DKH;
  const short* vtb = vt + (long)bh * (DKH * SEQ);
  const int lrow8 = lane >> 3;
  const int lcolsw = (((lane & 7) ^ lrow8) & 7) * 8;   // 16B XOR swizzle

// stage tile KT into buffer BSEL; K rows permuted per the frag8-PV layout
#define STAGE(KT, BSEL) do{                                                     \
  _Pragma("unroll")                                                             \
  for (int i_ = 0; i_ < 2; ++i_){                                               \
    int jj_ = w * 2 + i_;                                                       \
    int kr_ = 32 * (jj_ >> 2) + 8 * ((jj_ * 2 + (lrow8 >> 2)) & 3)              \
            + 4 * ((jj_ >> 1) & 1) + (lrow8 & 3);                               \
    GLOAD16(kb  + ((KT) * 64 + kr_) * DM + lcolsw,        &Ks[BSEL][jj_ * 512]);\
    GLOAD16(vtb + (jj_ * 8 + lrow8) * SEQ + (KT) * 64 + lcolsw,                 \
            &Vs[BSEL][jj_ * 512]);                                              \
  } }while(0)

#define COMPUTE(BS) do{                                                         \
  __builtin_amdgcn_s_setprio(1);                                                \
  f32x4 scT[2][4];                                                              \
  _Pragma("unroll") for (int mt = 0; mt < 2; ++mt)                              \
    _Pragma("unroll") for (int nt = 0; nt < 4; ++nt)                            \
      scT[mt][nt] = (f32x4){0.f, 0.f, 0.f, 0.f};                                \
  _Pragma("unroll") for (int ks = 0; ks < 2; ++ks){                             \
    _Pragma("unroll") for (int nt = 0; nt < 4; ++nt){                           \
      frag8 ak = *(const frag8*)&Ks[BS][(nt * 16 + l15) * 64 +                  \
                                        (((ks * 4 + quad) ^ (l15 & 7)) * 8)];   \
      _Pragma("unroll") for (int mt = 0; mt < 2; ++mt)                          \
        scT[mt][nt] = __builtin_amdgcn_mfma_f32_16x16x32_bf16(                  \
            ak, aq[mt][ks], scT[mt][nt], 0, 0, 0);                              \
    }                                                                           \
  }                                                                             \
  frag8 ap8[2][2];                                                              \
  _Pragma("unroll") for (int mt = 0; mt < 2; ++mt)                              \
    _Pragma("unroll") for (int c2 = 0; c2 < 2; ++c2){                           \
      frag8 p8;                                                                 \
      _Pragma("unroll") for (int hf = 0; hf < 2; ++hf)                          \
        _Pragma("unroll") for (int r = 0; r < 4; ++r){                          \
          float e = dev_exp2(scT[mt][2 * c2 + hf][r]);                          \
          p8[hf * 4 + r] = (short)((__float_as_uint(e) + 0x8000u) >> 16);       \
        }                                                                       \
      ap8[mt][c2] = p8;                                                         \
    }                                                                           \
  _Pragma("unroll") for (int c2 = 0; c2 < 2; ++c2){                             \
    _Pragma("unroll") for (int dt = 0; dt < 4; ++dt){                           \
      frag8 bv8 = *(const frag8*)&Vs[BS][(dt * 16 + l15) * 64 +                 \
                                         (((c2 * 4 + quad) ^ (l15 & 7)) * 8)];  \
      _Pragma("unroll") for (int mt = 0; mt < 2; ++mt)                          \
        O[mt][dt] = __builtin_amdgcn_mfma_f32_16x16x32_bf16(                    \
            ap8[mt][c2], bv8, O[mt][dt], 0, 0, 0);                              \
    }                                                                           \
    _Pragma("unroll") for (int mt = 0; mt < 2; ++mt)                            \
      Lacc[mt] = __builtin_amdgcn_mfma_f32_16x16x32_bf16(                       \
          ap8[mt][c2], ones8, Lacc[mt], 0, 0, 0);                               \
  }                                                                             \
  __builtin_amdgcn_s_setprio(0);                                                \
}while(0)

// one pipelined iteration: stage KT+2, wait for tile KT (vmcnt(8): leaves the
// 8 loads of tiles KT+1/KT+2 in flight), barrier (publish ALL waves' tile KT),
// fence (no read-hoist above barrier), compute, lgkm-drain + barrier (publish
// "done reading" before a later iter overwrites this buffer)
#define ITER(KT, BC, BSNEXT) do{                                                \
  STAGE((KT) + 2, BSNEXT);                                                      \
  asm volatile("s_waitcnt vmcnt(8)" ::: "memory");                              \
  __builtin_amdgcn_s_barrier();                                                 \
  LDSFENCE();                                                                   \
  COMPUTE(BC);                                                                  \
  asm volatile("s_waitcnt lgkmcnt(0)" ::: "memory");                            \
  __builtin_amdgcn_sched_barrier(0);                                            \
  __builtin_amdgcn_s_barrier();                                                 \
}while(0)

  STAGE(0, 0);
  STAGE(1, 1);
  for (int kt = 0; kt < SEQ / 64 - 2; kt += 3){   // 30 iterations, tiles 0..29
    ITER(kt,     0, 2);
    ITER(kt + 1, 1, 0);
    ITER(kt + 2, 2, 1);
  }
  // epilogue: tiles 30 (buf 0) and 31 (buf 1), no further staging
  asm volatile("s_waitcnt vmcnt(4)" ::: "memory");
  __builtin_amdgcn_s_barrier();
  LDSFENCE();
  COMPUTE(0);
  asm volatile("s_waitcnt vmcnt(0)" ::: "memory");
  __builtin_amdgcn_s_barrier();
  LDSFENCE();
  COMPUTE(1);

#undef ITER
#undef COMPUTE
#undef STAGE

  // epilogue: O/l -> comb bf16  (C-layout: row m=quad*4+r = qrow, col n=l15 = d)
  short* ob = comb + ((long)(b * SEQ + q0 + w * 32)) * DM + h * DKH;
#pragma unroll
  for (int mt = 0; mt < 2; ++mt){
#pragma unroll
    for (int r = 0; r < 4; ++r){
      float inv = 1.f / Lacc[mt][r];
#pragma unroll
      for (int dt = 0; dt < 4; ++dt)
        ob[(mt * 16 + quad * 4 + r) * DM + dt * 16 + l15] = (short)f2bf(O[mt][dt][r] * inv);
    }
  }
}

// ---------------- launch ----------------
extern "C" void kernel_launch(void* const* d_in, const int* in_sizes, int n_in,
                              void* d_out, int out_size, void* d_ws, size_t ws_size,
                              hipStream_t stream){
  const float* Q  = (const float*)d_in[0];
  const float* K  = (const float*)d_in[1];
  const float* V  = (const float*)d_in[2];
  const float* Wq = (const float*)d_in[3];
  const float* bq = (const float*)d_in[4];
  const float* Wk = (const float*)d_in[5];
  const float* bk = (const float*)d_in[6];
  const float* Wv = (const float*)d_in[7];
  const float* bv = (const float*)d_in[8];
  const float* Wo = (const float*)d_in[9];
  const float* bo = (const float*)d_in[10];
  float* out = (float*)d_out;

  const long TEN = (long)NB * SEQ * DM;   // 4194304 elements per activation tensor
  const long WEL = (long)DM * DM;         // 1048576 per weight
  short* ws   = (short*)d_ws;
  short* xc   = ws;                 // 3 * TEN
  short* wt   = xc + 3 * TEN;       // 4 * WEL
  short* qkv  = wt + 4 * WEL;       // 3 * TEN   (q, k, v projections, bf16)
  short* vtr  = qkv + 3 * TEN;      // TEN       (B,H,Dk,S)
  short* comb = vtr + TEN;          // TEN

  cast_qkv<<<dim3(4096, 1, 3), 256, 0, stream>>>(Q, K, V, xc);
  wtrans<<<dim3(32, 32, 4), 256, 0, stream>>>(Wq, Wk, Wv, Wo, wt);
  // projections: z=0 -> q (scaled by log2e/sqrt(Dk) for exp2 softmax), z=1 -> k, z=2 -> v
  gemm_bt<short><<<dim3(32, 8, 3), 256, 0, stream>>>(xc, TEN, wt, WEL, bq, bk, bv,
                                                     qkv, TEN, 0.125f * 1.44269504f);
  vtrans<<<dim3(32, 32), 256, 0, stream>>>(qkv + 2 * TEN, vtr);
  flash<<<dim3(16, 32), 256, 0, stream>>>(qkv, qkv + TEN, vtr, comb);
  gemm64_bt<float><<<dim3(64, 8), 256, 0, stream>>>(comb, wt + 3 * WEL, bo, out, 1.0f);
  (void)in_sizes; (void)n_in; (void)out_size; (void)ws_size;
}